// Round 2
// baseline (752.425 us; speedup 1.0000x reference)
//
#include <hip/hip_runtime.h>

// ---------------------------------------------------------------------------
// MultiHeadAttention_patch2: B*C = 262144 independent 4-token, 55-dim attns.
// All I/O is float32 (per the reference file's dtypes).
// Key identity (heads never split):
//   attn = softmax( xr M1 xr^T ),  M1 = scale * Wq^T Wk   (55x55)
//   out  = attn (xr P) + b,        P  = Wv^T Wfc^T        (55x55)
// Each sequence's 220 floats are contiguous in x; rearrange is a fixed
// permutation: local = p1*110 + p2*5 + h*10 + w,  token t=(p1,p2), d=(h,w).
//
// R1: removed runtime-indexed xreg[dp] (dynamic index -> whole array demoted
//     to scratch). w-loop unrolled; phase-A xc comes from LDS.
// R2: weight rows padded 55 -> 56 floats (224 B, 16B-aligned) so every row
//     is a clean 14 x float4 (global_load_dwordx4) stream; pad elements are
//     zeroed host-side-equivalent in setup_weights, xreg[55] = 0.
// ---------------------------------------------------------------------------

// DPP quad-perm broadcast of lane j within each group of 4 lanes.
// update_dpp with defined old (0) + bound_ctrl: fully-defined semantics.
#define QB(v, ctrl) __int_as_float(__builtin_amdgcn_update_dpp( \
    0, __float_as_int(v), (ctrl), 0xf, 0xf, true))

#define PAD 56  // padded row stride (floats); 56*4 = 224 B = 14 aligned float4

// ws layout (fp32):
//   [0, 3080)        M1T[dp][0..55]  (row stride 56, [55] = 0)
//   [3080, 6160)     PT [dp][0..55]  (row stride 56, [55] = 0)
//   [6160, 6215)     bias[55]
__global__ void setup_weights(const float* __restrict__ wq,
                              const float* __restrict__ wk,
                              const float* __restrict__ wv,
                              const float* __restrict__ wfc,
                              const float* __restrict__ bfc,
                              float* __restrict__ ws) {
    int i = blockIdx.x * blockDim.x + threadIdx.x;
    if (i < 55 * PAD) {
        int dp = i / PAD, d = i % PAD;
        if (d < 55) {
            float m1 = 0.f, p = 0.f;
            for (int e = 0; e < 48; ++e) {
                m1 += wq[e * 55 + d] * wk[e * 55 + dp];
                p  += wv[e * 55 + d] * wfc[dp * 48 + e];
            }
            ws[dp * PAD + d]            = m1 * 0.14433756729740643f; // 1/sqrt(48)
            ws[55 * PAD + dp * PAD + d] = p;
        } else {
            ws[dp * PAD + d]            = 0.f; // zero pads: avoid 0*garbage=NaN
            ws[55 * PAD + dp * PAD + d] = 0.f;
        }
    }
    if (i < 55) ws[110 * PAD + i] = bfc[i];
}

__global__ void __launch_bounds__(128)
attn_main(const float* __restrict__ x,
          const float* __restrict__ ws,
          float* __restrict__ out) {
    __shared__ __align__(16) float lds[32 * 220]; // 28160 B
    const float* __restrict__ M1T = ws;
    const float* __restrict__ PT  = ws + 55 * PAD;
    const float* __restrict__ BS  = ws + 110 * PAD;

    const int tid = threadIdx.x;
    const size_t seq0 = (size_t)blockIdx.x * 32;
    const float* __restrict__ xb = x + seq0 * 220;
    float* __restrict__ ob = out + seq0 * 220;

    // ---- stage 32 sequences (contiguous 28160 B) into LDS, vectorized ----
    {
        const uint4* __restrict__ src = (const uint4*)xb;
        uint4* dst = (uint4*)lds;
        #pragma unroll
        for (int it = 0; it < 14; ++it) {
            int i = tid + it * 128;
            if (i < 1760) dst[i] = src[i];
        }
    }
    __syncthreads();

    // thread = one token: lane-quad holds the 4 tokens of one sequence
    const int t      = tid & 3;
    const int sl     = tid >> 2;
    const int tokoff = (t >> 1) * 110 + (t & 1) * 5;
    const int base   = sl * 220 + tokoff;

    // own token's 55 features -> registers, permuted order d = h*5+w
    // (all indices below are compile-time constants -> stays in VGPRs)
    float xreg[PAD];
    #pragma unroll
    for (int d = 0; d < 55; ++d) {
        const int doff = (d / 5) * 10 + (d % 5);
        xreg[d] = lds[base + doff];
    }
    xreg[55] = 0.f; // pad lane; weight pad is also 0

    // ---- phase A: attn logits la[t'] = sum_dp (xr[t]·M1T[dp]) * xr[t'][dp]
    float la0 = 0.f, la1 = 0.f, la2 = 0.f, la3 = 0.f;
    for (int h = 0; h < 11; ++h) {
        // xc for this h's 5 dp values, re-read from LDS (runtime addressing
        // is legal in LDS; keeps xreg free of dynamic indices)
        float xc[5];
        #pragma unroll
        for (int w = 0; w < 5; ++w) xc[w] = lds[base + h * 10 + w];

        #pragma unroll
        for (int w = 0; w < 5; ++w) {
            const int dp = h * 5 + w;
            // wave-uniform, 16B-aligned row -> 14x global_load_dwordx4
            const float4* __restrict__ m4 = (const float4*)(M1T + dp * PAD);
            float a0 = 0.f, a1 = 0.f, a2 = 0.f, a3 = 0.f;
            #pragma unroll
            for (int d4 = 0; d4 < 14; ++d4) {
                const float4 mm = m4[d4];
                a0 = fmaf(xreg[4 * d4 + 0], mm.x, a0);
                a1 = fmaf(xreg[4 * d4 + 1], mm.y, a1);
                a2 = fmaf(xreg[4 * d4 + 2], mm.z, a2);
                a3 = fmaf(xreg[4 * d4 + 3], mm.w, a3);
            }
            const float t1 = (a0 + a1) + (a2 + a3);
            la0 = fmaf(t1, QB(xc[w], 0x00), la0);
            la1 = fmaf(t1, QB(xc[w], 0x55), la1);
            la2 = fmaf(t1, QB(xc[w], 0xAA), la2);
            la3 = fmaf(t1, QB(xc[w], 0xFF), la3);
        }
    }

    // ---- softmax over the 4 logits ----
    const float mx = fmaxf(fmaxf(la0, la1), fmaxf(la2, la3));
    const float e0 = __expf(la0 - mx), e1 = __expf(la1 - mx);
    const float e2 = __expf(la2 - mx), e3 = __expf(la3 - mx);
    const float inv = 1.0f / (e0 + e1 + e2 + e3);
    const float p0 = e0 * inv, p1 = e1 * inv, p2 = e2 * inv, p3 = e3 * inv;

    __syncthreads(); // phase B overwrites the LDS x buffer with outputs

    // ---- phase B: out[t][dp] = b[dp] + sum_t' p[t'] * (xr[t']·PT[dp]) ----
    for (int h = 0; h < 11; ++h) {
        #pragma unroll
        for (int w = 0; w < 5; ++w) {
            const int dp = h * 5 + w;
            const float4* __restrict__ pc4 = (const float4*)(PT + dp * PAD);
            float a0 = 0.f, a1 = 0.f, a2 = 0.f, a3 = 0.f;
            #pragma unroll
            for (int d4 = 0; d4 < 14; ++d4) {
                const float4 mm = pc4[d4];
                a0 = fmaf(xreg[4 * d4 + 0], mm.x, a0);
                a1 = fmaf(xreg[4 * d4 + 1], mm.y, a1);
                a2 = fmaf(xreg[4 * d4 + 2], mm.z, a2);
                a3 = fmaf(xreg[4 * d4 + 3], mm.w, a3);
            }
            const float t2 = (a0 + a1) + (a2 + a3); // T2[own t][dp]
            float o = BS[dp];
            o = fmaf(p0, QB(t2, 0x00), o);
            o = fmaf(p1, QB(t2, 0x55), o);
            o = fmaf(p2, QB(t2, 0xAA), o);
            o = fmaf(p3, QB(t2, 0xFF), o);
            lds[base + h * 10 + w] = o;
        }
    }
    __syncthreads();

    // ---- store 32 sequences back, vectorized ----
    {
        const uint4* __restrict__ src = (const uint4*)lds;
        uint4* dst = (uint4*)ob;
        #pragma unroll
        for (int it = 0; it < 14; ++it) {
            int i = tid + it * 128;
            if (i < 1760) dst[i] = src[i];
        }
    }
}

extern "C" void kernel_launch(void* const* d_in, const int* in_sizes, int n_in,
                              void* d_out, int out_size, void* d_ws, size_t ws_size,
                              hipStream_t stream) {
    const float* x   = (const float*)d_in[0];
    const float* wq  = (const float*)d_in[1];
    const float* wk  = (const float*)d_in[2];
    const float* wv  = (const float*)d_in[3];
    const float* wfc = (const float*)d_in[4];
    const float* bfc = (const float*)d_in[5];
    float* ws = (float*)d_ws; // needs 6215 floats = 24860 B

    const int nseq = out_size / 220;   // 262144
    const int nblk = nseq / 32;        // 8192

    hipLaunchKernelGGL(setup_weights, dim3(13), dim3(256), 0, stream,
                       wq, wk, wv, wfc, bfc, ws);
    hipLaunchKernelGGL(attn_main, dim3(nblk), dim3(128), 0, stream,
                       x, ws, (float*)d_out);
}

// Round 3
// 719.705 us; speedup vs baseline: 1.0455x; 1.0455x over previous
//
#include <hip/hip_runtime.h>

// ---------------------------------------------------------------------------
// MultiHeadAttention_patch2: B*C = 262144 independent 4-token, 55-dim attns.
// All I/O is float32 (per the reference file's dtypes).
// Key identity (heads never split):
//   attn = softmax( xr M1 xr^T ),  M1 = scale * Wq^T Wk   (55x55)
//   out  = attn (xr P) + b,        P  = Wv^T Wfc^T        (55x55)
// Each sequence's 220 floats are contiguous in x; rearrange is a fixed
// permutation: local = p1*110 + p2*5 + h*10 + w,  token t=(p1,p2), d=(h,w).
//
// R1: removed runtime-indexed xreg[dp] (dynamic index -> scratch demotion).
// R2: weight rows padded 55 -> 56 floats (16B-aligned float4 stream).
// R3: NO LDS. R2 measured 490us with LDS=28160B capping occupancy at
//     5 blocks/CU = 2.5 waves/SIMD -> dependent weight-load latency exposed
//     (fp32 VALU floor is ~92us; we ran at ~17% issue efficiency).
//     Each thread now loads its token's 11x5-float runs directly from global
//     (align(4) float4 + scalar; gfx9+ supports 4B-aligned dwordx4), re-reads
//     its own row per h for xc (L1 hit), and stores output runs directly.
//     No __syncthreads, LDS_Block_Size=0, occupancy becomes VGPR-bound.
// ---------------------------------------------------------------------------

// DPP quad-perm broadcast of lane j within each group of 4 lanes.
#define QB(v, ctrl) __int_as_float(__builtin_amdgcn_update_dpp( \
    0, __float_as_int(v), (ctrl), 0xf, 0xf, true))

#define PAD 56  // padded weight row stride (floats); 224 B = 14 aligned float4

typedef float vf4 __attribute__((ext_vector_type(4)));          // 16B-aligned
typedef float uvf4 __attribute__((ext_vector_type(4), aligned(4))); // 4B-aligned

// ws layout (fp32):
//   [0, 3080)        M1T[dp][0..55]  (row stride 56, [55] = 0)
//   [3080, 6160)     PT [dp][0..55]  (row stride 56, [55] = 0)
//   [6160, 6215)     bias[55]
__global__ void setup_weights(const float* __restrict__ wq,
                              const float* __restrict__ wk,
                              const float* __restrict__ wv,
                              const float* __restrict__ wfc,
                              const float* __restrict__ bfc,
                              float* __restrict__ ws) {
    int i = blockIdx.x * blockDim.x + threadIdx.x;
    if (i < 55 * PAD) {
        int dp = i / PAD, d = i % PAD;
        if (d < 55) {
            float m1 = 0.f, p = 0.f;
            for (int e = 0; e < 48; ++e) {
                m1 += wq[e * 55 + d] * wk[e * 55 + dp];
                p  += wv[e * 55 + d] * wfc[dp * 48 + e];
            }
            ws[dp * PAD + d]            = m1 * 0.14433756729740643f; // 1/sqrt(48)
            ws[55 * PAD + dp * PAD + d] = p;
        } else {
            ws[dp * PAD + d]            = 0.f; // zero pads: avoid 0*garbage=NaN
            ws[55 * PAD + dp * PAD + d] = 0.f;
        }
    }
    if (i < 55) ws[110 * PAD + i] = bfc[i];
}

__global__ void __launch_bounds__(256)
attn_main(const float* __restrict__ x,
          const float* __restrict__ ws,
          float* __restrict__ out) {
    const float* __restrict__ M1T = ws;
    const float* __restrict__ PT  = ws + 55 * PAD;
    const float* __restrict__ BS  = ws + 110 * PAD;

    const int tid = threadIdx.x;
    const int t   = tid & 3;                                  // token in seq
    const size_t sq = ((size_t)blockIdx.x * 256 + tid) >> 2;  // sequence id
    const int tokoff = (t >> 1) * 110 + (t & 1) * 5;
    const float* __restrict__ xt = x   + sq * 220 + tokoff;
    float* __restrict__ ot       = out + sq * 220 + tokoff;

    // ---- own token's 55 features -> registers (constant indices only) ----
    // 11 runs of 5 contiguous floats, run h at byte offset h*40.
    float xreg[PAD];
    #pragma unroll
    for (int h = 0; h < 11; ++h) {
        const uvf4 v = *(const uvf4*)(xt + h * 10);
        xreg[5 * h + 0] = v.x;
        xreg[5 * h + 1] = v.y;
        xreg[5 * h + 2] = v.z;
        xreg[5 * h + 3] = v.w;
        xreg[5 * h + 4] = xt[h * 10 + 4];
    }
    xreg[55] = 0.f; // pad lane; weight pad is also 0

    // ---- phase A: la[t'] = sum_dp (xr[t]·M1T[dp]) * xr[t'][dp] ----
    float la0 = 0.f, la1 = 0.f, la2 = 0.f, la3 = 0.f;
    for (int h = 0; h < 11; ++h) {
        // own row h re-read from global (same addresses as the xreg load ->
        // guaranteed L1 hit). Keeps xreg free of runtime indices.
        const uvf4 c4 = *(const uvf4*)(xt + h * 10);
        const float c5 = xt[h * 10 + 4];
        const float xc[5] = {c4.x, c4.y, c4.z, c4.w, c5};

        #pragma unroll
        for (int w = 0; w < 5; ++w) {
            const int dp = h * 5 + w;
            // wave-uniform 16B-aligned weight row
            const vf4* __restrict__ m4 = (const vf4*)(M1T + dp * PAD);
            float a0 = 0.f, a1 = 0.f, a2 = 0.f, a3 = 0.f;
            #pragma unroll
            for (int d4 = 0; d4 < 14; ++d4) {
                const vf4 mm = m4[d4];
                a0 = fmaf(xreg[4 * d4 + 0], mm.x, a0);
                a1 = fmaf(xreg[4 * d4 + 1], mm.y, a1);
                a2 = fmaf(xreg[4 * d4 + 2], mm.z, a2);
                a3 = fmaf(xreg[4 * d4 + 3], mm.w, a3);
            }
            const float t1 = (a0 + a1) + (a2 + a3);
            la0 = fmaf(t1, QB(xc[w], 0x00), la0);
            la1 = fmaf(t1, QB(xc[w], 0x55), la1);
            la2 = fmaf(t1, QB(xc[w], 0xAA), la2);
            la3 = fmaf(t1, QB(xc[w], 0xFF), la3);
        }
    }

    // ---- softmax over the 4 logits ----
    const float mx = fmaxf(fmaxf(la0, la1), fmaxf(la2, la3));
    const float e0 = __expf(la0 - mx), e1 = __expf(la1 - mx);
    const float e2 = __expf(la2 - mx), e3 = __expf(la3 - mx);
    const float inv = 1.0f / (e0 + e1 + e2 + e3);
    const float p0 = e0 * inv, p1 = e1 * inv, p2 = e2 * inv, p3 = e3 * inv;

    // ---- phase B: out[t][dp] = b[dp] + sum_t' p[t'] * (xr[t']·PT[dp]) ----
    for (int h = 0; h < 11; ++h) {
        float o[5];
        #pragma unroll
        for (int w = 0; w < 5; ++w) {
            const int dp = h * 5 + w;
            const vf4* __restrict__ pc4 = (const vf4*)(PT + dp * PAD);
            float a0 = 0.f, a1 = 0.f, a2 = 0.f, a3 = 0.f;
            #pragma unroll
            for (int d4 = 0; d4 < 14; ++d4) {
                const vf4 mm = pc4[d4];
                a0 = fmaf(xreg[4 * d4 + 0], mm.x, a0);
                a1 = fmaf(xreg[4 * d4 + 1], mm.y, a1);
                a2 = fmaf(xreg[4 * d4 + 2], mm.z, a2);
                a3 = fmaf(xreg[4 * d4 + 3], mm.w, a3);
            }
            const float t2 = (a0 + a1) + (a2 + a3); // T2[own t][dp]
            float oo = BS[dp]; // uniform scalar load
            oo = fmaf(p0, QB(t2, 0x00), oo);
            oo = fmaf(p1, QB(t2, 0x55), oo);
            oo = fmaf(p2, QB(t2, 0xAA), oo);
            oo = fmaf(p3, QB(t2, 0xFF), oo);
            o[w] = oo;
        }
        // direct store: align(4) float4 + scalar (L2 merges partial lines)
        uvf4 st;
        st.x = o[0]; st.y = o[1]; st.z = o[2]; st.w = o[3];
        *(uvf4*)(ot + h * 10) = st;
        ot[h * 10 + 4] = o[4];
    }
}

extern "C" void kernel_launch(void* const* d_in, const int* in_sizes, int n_in,
                              void* d_out, int out_size, void* d_ws, size_t ws_size,
                              hipStream_t stream) {
    const float* x   = (const float*)d_in[0];
    const float* wq  = (const float*)d_in[1];
    const float* wk  = (const float*)d_in[2];
    const float* wv  = (const float*)d_in[3];
    const float* wfc = (const float*)d_in[4];
    const float* bfc = (const float*)d_in[5];
    float* ws = (float*)d_ws; // needs 6215 floats = 24860 B

    const int nseq = out_size / 220;   // 262144
    const int nblk = nseq / 64;        // 4096 blocks of 256 threads (64 seqs)

    hipLaunchKernelGGL(setup_weights, dim3(13), dim3(256), 0, stream,
                       wq, wk, wv, wfc, bfc, ws);
    hipLaunchKernelGGL(attn_main, dim3(nblk), dim3(256), 0, stream,
                       x, ws, (float*)d_out);
}